// Round 15
// baseline (284.278 us; speedup 1.0000x reference)
//
#include <hip/hip_runtime.h>

// B=8, T=1024, D=1024, H=16, DH=64.
// Column softmax (axis=-2). rcpL folded into V (Vts); C2 folded into Q-rows
// of Wqkv (R11). K3: S transposed + k-permuted Vts -> PV = 1 K=32 MFMA/jd.
// R14/R15: K1 = gemm256 -- 256x256 tile, BK=64, 8 waves, 4-phase staggered
// half-K pipeline with counted vmcnt(8) (never 0 in steady state),
// sw32-swizzled [256][32] half-tiles in 8 STATIC LDS arrays (128 KB),
// setprio around each 16-MFMA cluster. Epilogue tiles: vmcnt(4)/vmcnt(0).
// R15 = byte-identical resubmit of R14 (container-level failure, no GPU
// verdict; audit found no hang/fault path: uniform barriers, reachable
// waits, in-bounds, 128KB LDS = m201 budget, rule-18 fences in place).
// K4 keeps the proven 128^2 static-dbuf gemm_bt. K2/K3/convert frozen (R12).

typedef __bf16 bf16_t;
typedef __bf16 bf16x8 __attribute__((ext_vector_type(8)));
typedef __bf16 bf16x4 __attribute__((ext_vector_type(4)));
typedef float f32x4 __attribute__((ext_vector_type(4)));
typedef unsigned short u16x8 __attribute__((ext_vector_type(8)));

#define DEV __device__ __forceinline__
#define C2 0.18033688f  // DH^-0.5 * log2(e), folded into Q-rows of Wqkv

DEV void gld_lds16(const bf16_t* g, bf16_t* l) {
  __builtin_amdgcn_global_load_lds(
      (const __attribute__((address_space(1))) unsigned int*)g,
      (__attribute__((address_space(3))) unsigned int*)l, 16, 0, 0);
}

DEV float exp2c(float x) { return __builtin_amdgcn_exp2f(fminf(x, 30.f)); }
DEV float sanit(float v) { return (v == v) ? fminf(fmaxf(v, -1e4f), 1e4f) : 0.f; }

// Swizzled chunk offsets (16B chunks). Swizzle baked into the staging
// GLOBAL address so the LDS side stays linear (global_load_lds req).
DEV int sw64(int r, int kc) { return r * 64 + (((kc ^ (r + (r >> 3))) & 7) << 3); }
DEV int sw32(int r, int kc) { return r * 32 + (((kc ^ r ^ (r >> 2)) & 3) << 3); }

DEV f32x4 mfma16(bf16x8 a, bf16x8 b, f32x4 c) {
  return __builtin_amdgcn_mfma_f32_16x16x32_bf16(a, b, c, 0, 0, 0);
}

DEV unsigned ldsa(const bf16_t* p) { return (unsigned)(size_t)p; }

DEV bf16x8 dsr128(unsigned addr) {
  bf16x8 r;
  asm volatile("ds_read_b128 %0, %1" : "=v"(r) : "v"(addr));
  return r;
}

// ---- dtype probe ------------------------------------------------------------
__global__ void detect_dtype(const unsigned short* x, int* flag) {
  __shared__ int smax;
  if (threadIdx.x == 0) smax = 0;
  __syncthreads();
  int m = 0;
  for (int i = threadIdx.x; i < 16384; i += 256) {
    int e = (x[i] >> 7) & 0xFF;
    m = m > e ? m : e;
  }
  atomicMax(&smax, m);
  __syncthreads();
  if (threadIdx.x == 0) *flag = (smax >= 160) ? 1 : 0;
}

// ---- canonicalize inputs to bf16; scale Q-rows of Wqkv by C2 ---------------
__global__ void convert_in(const void* __restrict__ x, const void* __restrict__ wq,
                           const void* __restrict__ wp, bf16_t* __restrict__ xb,
                           bf16_t* __restrict__ wqb, bf16_t* __restrict__ wpb,
                           const int* __restrict__ flag) {
  int i = blockIdx.x * 256 + threadIdx.x;  // vec8 index, total 1572864
  const void* src;
  bf16_t* dst;
  int off;
  bool isQ = false;
  if (i < 1048576) { src = x; dst = xb; off = i; }
  else if (i < 1441792) {
    src = wq; dst = wqb; off = i - 1048576;
    isQ = off < 131072;  // rows 0..1023 of Wqkv
  } else { src = wp; dst = wpb; off = i - 1441792; }
  if (*flag) {
    const float s = isQ ? C2 : 1.0f;
    const float4* sp = (const float4*)src;
    float4 a = sp[off * 2], b = sp[off * 2 + 1];
    bf16x8 o;
    o[0] = (bf16_t)(a.x * s); o[1] = (bf16_t)(a.y * s);
    o[2] = (bf16_t)(a.z * s); o[3] = (bf16_t)(a.w * s);
    o[4] = (bf16_t)(b.x * s); o[5] = (bf16_t)(b.y * s);
    o[6] = (bf16_t)(b.z * s); o[7] = (bf16_t)(b.w * s);
    *(bf16x8*)(dst + (size_t)off * 8) = o;
  } else {
    u16x8 v = ((const u16x8*)src)[off];
    if (isQ) {
      bf16x8 bsrc = __builtin_bit_cast(bf16x8, v);
      bf16x8 o;
#pragma unroll
      for (int t = 0; t < 8; ++t) o[t] = (bf16_t)((float)bsrc[t] * C2);
      *(bf16x8*)(dst + (size_t)off * 8) = o;
    } else {
      ((u16x8*)dst)[off] = v;
    }
  }
}

// ===== K1 GEMM: 256x256 tile, BK=64, staggered half-K counted-vmcnt pipe ====
// C[m][n] = sum_k A[m][k]*B[n][k]; A=xb (lda 1024), B=Wqkvb (ldb 1024),
// C=qkv (ldc 3072), M=8192 N=3072 K=1024 (NT=16 tiles). Grid (12,32)=384.
// Pipeline (per tile t, 4 phases; half h = K-half, mh = M-half quadrant):
//  p0: vmcnt(8)+bar | stage S(t+1,h1).sub0 | read h0,mh0 | 16 MFMA
//  p1:          bar | stage S(t+1,h1).sub1 | read h0,mh1 | 16 MFMA
//  p2: vmcnt(8)+bar | stage S(t+2,h0).sub0 | read h1,mh0 | 16 MFMA
//  p3:          bar | stage S(t+2,h0).sub1 | read h1,mh1 | 16 MFMA
// Wait counts: at p0, newer-in-flight = S(t,h1)[4]+S(t+1,h0)[4] = 8;
// at p2, = S(t+1,h0)[4]+S(t+1,h1)[4] = 8. Last tile: 4 / 0.
// WAR: dest of S(t+1,h1) last read in t-1.p3 (all waves past p0 barrier);
// dest of S(t+2,h0) last read in t.p1 (all waves past p2 barrier).
__global__ __launch_bounds__(512, 2)
void gemm256(const bf16_t* __restrict__ A, const bf16_t* __restrict__ Bm,
             bf16_t* __restrict__ Cb) {
  __shared__ bf16_t aL00[256 * 32];  // buf0 half0 (k 0..31 of tile)
  __shared__ bf16_t aL01[256 * 32];  // buf0 half1
  __shared__ bf16_t aL10[256 * 32];  // buf1 half0
  __shared__ bf16_t aL11[256 * 32];  // buf1 half1
  __shared__ bf16_t bL00[256 * 32];
  __shared__ bf16_t bL01[256 * 32];
  __shared__ bf16_t bL10[256 * 32];
  __shared__ bf16_t bL11[256 * 32];
  const int tid = threadIdx.x;
  const int wave = tid >> 6, lane = tid & 63;
  const int l = lane & 15, quad = lane >> 4;
  const int wr = wave >> 2, wc = wave & 3;  // 2 x 4 wave grid
  const int bid = blockIdx.y * gridDim.x + blockIdx.x;  // gridDim=(12,32)
  const int sb = (bid & 7) * 48 + (bid >> 3);           // 384/8 = 48
  const int row0 = (sb / 12) * 256, col0 = (sb % 12) * 256;

  f32x4 acc[8][4];
#pragma unroll
  for (int i = 0; i < 8; ++i)
#pragma unroll
    for (int j = 0; j < 4; ++j) acc[i][j] = f32x4{0.f, 0.f, 0.f, 0.f};

  // One sub-stage: 1 A-gld + 1 B-gld per thread (512 thr cover 256x32 x2).
#define STAGE1(XA, XB, koff, s)                                               \
  {                                                                           \
    int n = (s) * 512 + tid;                                                  \
    int r = n >> 2;                                                           \
    int kc = ((n & 3) ^ r ^ (r >> 2)) & 3;                                    \
    gld_lds16(A + (size_t)(row0 + r) * 1024 + (koff) + kc * 8, (XA) + n * 8); \
    gld_lds16(Bm + (size_t)(col0 + r) * 1024 + (koff) + kc * 8, (XB) + n * 8);\
  }

  // One phase's compute: 4 A-frags + 4 B-frags, 16 MFMA into quadrant mh.
#define QPHASE(XA, XB, mh)                                                    \
  {                                                                           \
    bf16x8 af[4], bfv[4];                                                     \
    _Pragma("unroll") for (int mi = 0; mi < 4; ++mi) af[mi] =                 \
        dsr128(ldsa(&(XA)[sw32(wr * 128 + (mh) * 64 + mi * 16 + l, quad)]));  \
    _Pragma("unroll") for (int ni = 0; ni < 4; ++ni) bfv[ni] =                \
        dsr128(ldsa(&(XB)[sw32(wc * 64 + ni * 16 + l, quad)]));               \
    asm volatile("s_waitcnt lgkmcnt(0)" ::: "memory");                        \
    __builtin_amdgcn_sched_barrier(0);                                        \
    __builtin_amdgcn_s_setprio(1);                                            \
    _Pragma("unroll") for (int mi = 0; mi < 4; ++mi)                          \
        _Pragma("unroll") for (int ni = 0; ni < 4; ++ni)                      \
            acc[(mh) * 4 + mi][ni] =                                          \
                mfma16(af[mi], bfv[ni], acc[(mh) * 4 + mi][ni]);              \
    __builtin_amdgcn_s_setprio(0);                                            \
  }

#define TILE(A0, A1, B0, B1, NA1, NB1, t, S1ON, S2ON, VM0, VM2)               \
  {                                                                           \
    asm volatile("s_waitcnt " VM0 ::: "memory");                              \
    __builtin_amdgcn_sched_barrier(0);                                        \
    __builtin_amdgcn_s_barrier();                                             \
    if (S1ON) STAGE1(NA1, NB1, (t) * 64 + 96, 0);                             \
    QPHASE(A0, B0, 0);                                                        \
    __builtin_amdgcn_s_barrier();                                             \
    if (S1ON) STAGE1(NA1, NB1, (t) * 64 + 96, 1);                             \
    QPHASE(A0, B0, 1);                                                        \
    asm volatile("s_waitcnt " VM2 ::: "memory");                              \
    __builtin_amdgcn_sched_barrier(0);                                        \
    __builtin_amdgcn_s_barrier();                                             \
    if (S2ON) STAGE1(A0, B0, (t) * 64 + 128, 0);                              \
    QPHASE(A1, B1, 0);                                                        \
    __builtin_amdgcn_s_barrier();                                             \
    if (S2ON) STAGE1(A0, B0, (t) * 64 + 128, 1);                              \
    QPHASE(A1, B1, 1);                                                        \
  }

  // prologue: S(0,h0), S(0,h1), S(1,h0) = 12 gld/thread in flight
  STAGE1(aL00, bL00, 0, 0);
  STAGE1(aL00, bL00, 0, 1);
  STAGE1(aL01, bL01, 32, 0);
  STAGE1(aL01, bL01, 32, 1);
  STAGE1(aL10, bL10, 64, 0);
  STAGE1(aL10, bL10, 64, 1);

  for (int it = 0; it < 7; ++it) {
    const int t0 = 2 * it, t1 = 2 * it + 1;
    TILE(aL00, aL01, bL00, bL01, aL11, bL11, t0, 1, 1, "vmcnt(8)", "vmcnt(8)");
    TILE(aL10, aL11, bL10, bL11, aL01, bL01, t1, 1, 1, "vmcnt(8)", "vmcnt(8)");
  }
  // t=14: stage S(15,h1) only; t=15: no stages, tighter waits.
  TILE(aL00, aL01, bL00, bL01, aL11, bL11, 14, 1, 0, "vmcnt(8)", "vmcnt(8)");
  TILE(aL10, aL11, bL10, bL11, aL01, bL01, 15, 0, 0, "vmcnt(4)", "vmcnt(0)");

#undef TILE
#undef QPHASE
#undef STAGE1

  // epilogue: m = row0 + wr*128 + mt*16 + quad*4 + tt; n = col0 + wc*64 +
  // ni*16 + l  (16x16x32 D-layout: row = quad*4+t, col = l)
#pragma unroll
  for (int mt = 0; mt < 8; ++mt) {
    int rbase = row0 + wr * 128 + mt * 16 + quad * 4;
#pragma unroll
    for (int ni = 0; ni < 4; ++ni) {
      int cc = col0 + wc * 64 + ni * 16 + l;
#pragma unroll
      for (int tt = 0; tt < 4; ++tt)
        Cb[(size_t)(rbase + tt) * 3072 + cc] = (bf16_t)sanit(acc[mt][ni][tt]);
    }
  }
}

// --------- K4 GEMM: 128x128 tile, BK=64x2 static dbuf (R7 body) -------------
__global__ __launch_bounds__(256, 2)
void gemm_bt(const bf16_t* __restrict__ A, int lda, const bf16_t* __restrict__ B,
             bf16_t* __restrict__ Cb, float* __restrict__ Cf, int ldc,
             int K, const int* __restrict__ f32flag) {
  __shared__ bf16_t sA0[128 * 64];
  __shared__ bf16_t sB0[128 * 64];
  __shared__ bf16_t sA1[128 * 64];
  __shared__ bf16_t sB1[128 * 64];
  const int tid = threadIdx.x;
  const int wave = tid >> 6, lane = tid & 63;
  const int l = lane & 15, quad = lane >> 4;
  const int nwg = gridDim.x * gridDim.y;
  const int bid = blockIdx.y * gridDim.x + blockIdx.x;
  const int sb = (bid & 7) * (nwg >> 3) + (bid >> 3);
  const int row0 = (sb / gridDim.x) * 128, col0 = (sb % gridDim.x) * 128;
  const int wm = (wave >> 1) * 64, wn = (wave & 1) * 64;
  f32x4 acc[4][4];
#pragma unroll
  for (int i = 0; i < 4; ++i)
#pragma unroll
    for (int j = 0; j < 4; ++j) acc[i][j] = f32x4{0.f, 0.f, 0.f, 0.f};

#define STAGE_G(sa, sb_, kk)                                                  \
  {                                                                           \
    _Pragma("unroll") for (int t = 0; t < 4; ++t) {                           \
      int n = t * 256 + tid;                                                  \
      int r = n >> 3;                                                         \
      int kc = ((n & 7) ^ (r + (r >> 3))) & 7;                                \
      gld_lds16(A + (size_t)(row0 + r) * lda + (kk) + kc * 8, (sa) + n * 8);  \
      gld_lds16(B + (size_t)(col0 + r) * K + (kk) + kc * 8, (sb_) + n * 8);   \
    }                                                                         \
  }

#define COMPUTE_G(sa, sb_)                                                    \
  {                                                                           \
    _Pragma("unroll") for (int ks = 0; ks < 2; ++ks) {                        \
      bf16x8 af[4], bfr[4];                                                   \
      _Pragma("unroll") for (int i = 0; i < 4; ++i) af[i] =                   \
          *(const bf16x8*)&(sa)[sw64(wm + i * 16 + l, ks * 4 + quad)];        \
      _Pragma("unroll") for (int j = 0; j < 4; ++j) bfr[j] =                  \
          *(const bf16x8*)&(sb_)[sw64(wn + j * 16 + l, ks * 4 + quad)];       \
      _Pragma("unroll") for (int i = 0; i < 4; ++i)                           \
          _Pragma("unroll") for (int j = 0; j < 4; ++j) acc[i][j] =           \
              mfma16(af[i], bfr[j], acc[i][j]);                               \
    }                                                                         \
  }

  STAGE_G(sA0, sB0, 0);
  for (int k0 = 0; k0 < K; k0 += 128) {
    __syncthreads();
    if (k0 + 64 < K) STAGE_G(sA1, sB1, k0 + 64);
    COMPUTE_G(sA0, sB0);
    __syncthreads();
    if (k0 + 128 < K) STAGE_G(sA0, sB0, k0 + 128);
    COMPUTE_G(sA1, sB1);
  }
#undef STAGE_G
#undef COMPUTE_G

  const bool of32 = (f32flag != nullptr) && (*f32flag != 0);
#pragma unroll
  for (int i = 0; i < 4; ++i) {
    int rr = row0 + wm + i * 16 + quad * 4;
#pragma unroll
    for (int j = 0; j < 4; ++j) {
      int cc = col0 + wn + j * 16 + l;
#pragma unroll
      for (int t = 0; t < 4; ++t) {
        float v = sanit(acc[i][j][t]);
        size_t idx = (size_t)(rr + t) * ldc + cc;
        if (of32) Cf[idx] = v; else Cb[idx] = (bf16_t)v;
      }
    }
  }
}

// ------------- K2: column sumexp L[k]; write Vts = V * (1/L) -----------------
__global__ __launch_bounds__(256, 4)
void attn_stats(const bf16_t* __restrict__ qkv, bf16_t* __restrict__ Vts) {
  __shared__ bf16_t sK[128 * 64];
  __shared__ bf16_t sV[128 * 64];
  __shared__ float sL[128];
  const int bh = blockIdx.x, kt = blockIdx.y;
  const int b = bh >> 4, h = bh & 15;
  const int tid = threadIdx.x, wave = tid >> 6, lane = tid & 63;
  const int l = lane & 15, quad = lane >> 4;
  const size_t rowK = (size_t)b * 1024 + kt * 128;

#pragma unroll
  for (int t = 0; t < 4; ++t) {
    int base = wave * 256 + t * 64;
    int n = base + lane;
    int r = n >> 3;
    int kc = ((n & 7) ^ (r + (r >> 3))) & 7;
    gld_lds16(qkv + (rowK + r) * 3072 + 2048 + h * 64 + kc * 8, sV + base * 8);
    gld_lds16(qkv + (rowK + r) * 3072 + 1024 + h * 64 + kc * 8, sK + base * 8);
  }
  if (tid < 128) sL[tid] = 0.f;
  __syncthreads();

  float accj[8];
#pragma unroll
  for (int j = 0; j < 8; ++j) accj[j] = 0.f;

  for (int qt = 0; qt < 8; ++qt) {
    bf16x8 aq[2][2];
#pragma unroll
    for (int i = 0; i < 2; ++i)
#pragma unroll
      for (int ks = 0; ks < 2; ++ks)
        aq[i][ks] = *(const bf16x8*)&qkv[((size_t)b * 1024 + qt * 128 + wave * 32 +
                                          i * 16 + l) * 3072 + h * 64 +
                                         (ks * 4 + quad) * 8];
#pragma unroll
    for (int j = 0; j < 8; ++j) {
      f32x4 s0 = {0.f, 0.f, 0.f, 0.f}, s1 = {0.f, 0.f, 0.f, 0.f};
#pragma unroll
      for (int ks = 0; ks < 2; ++ks) {
        bf16x8 bk = *(const bf16x8*)&sK[sw64(j * 16 + l, ks * 4 + quad)];
        s0 = mfma16(aq[0][ks], bk, s0);
        s1 = mfma16(aq[1][ks], bk, s1);
      }
#pragma unroll
      for (int t = 0; t < 4; ++t)
        accj[j] += exp2c(s0[t]) + exp2c(s1[t]);
    }
  }
#pragma unroll
  for (int j = 0; j < 8; ++j) {
    float v = accj[j];
    v += __shfl_xor(v, 16);
    v += __shfl_xor(v, 32);
    if (lane < 16) atomicAdd(&sL[j * 16 + l], v);
  }
  __syncthreads();
  if (tid < 128) sL[tid] = 1.0f / fmaxf(sL[tid], 1e-20f);
  __syncthreads();

#pragma unroll
  for (int t = 0; t < 4; ++t) {
    int u = t * 256 + tid;
    int d = u >> 4, k0 = (u & 15) * 8;
    bf16x8 pk;
#pragma unroll
    for (int i = 0; i < 8; ++i) {
      int kl = (k0 & ~31) | ((i >> 2) << 4) | (((k0 >> 3) & 3) << 2) | (i & 3);
      float v = (float)sV[sw64(kl, d >> 3) + (d & 7)];
      pk[i] = (bf16_t)(v * sL[kl]);
    }
    *(bf16x8*)&Vts[((size_t)bh * 64 + d) * 1024 + kt * 128 + k0] = pk;
  }
}

// ------------- K3: O[q][d] = sum_k exp2(Ss[q,k]) * Vts[d][k] -----------------
__global__ __launch_bounds__(512, 4)
void attn_out_k(const bf16_t* __restrict__ qkv, const bf16_t* __restrict__ Vts,
                bf16_t* __restrict__ attn) {
  __shared__ bf16_t sK[2][128 * 64];
  __shared__ bf16_t sV[2][64 * 128];
  const int bh = blockIdx.x, qt = blockIdx.y;
  const int b = bh >> 4, h = bh & 15;
  const int tid = threadIdx.x, wave = tid >> 6, lane = tid & 63;
  const int l = lane & 15, quad = lane >> 4;
  const bf16_t* qbase = qkv + (size_t)b * 3145728 + h * 64;
  const bf16_t* vbase = Vts + (size_t)bh * 65536;

  bf16x8 bq[2][2];
#pragma unroll
  for (int i = 0; i < 2; ++i)
#pragma unroll
    for (int ks = 0; ks < 2; ++ks)
      bq[i][ks] = *(const bf16x8*)&qbase[(size_t)(qt * 256 + wave * 32 + i * 16 + l) *
                                             3072 + ks * 32 + quad * 8];
  f32x4 o[2][4];
#pragma unroll
  for (int i = 0; i < 2; ++i)
#pragma unroll
    for (int jd = 0; jd < 4; ++jd) o[i][jd] = f32x4{0.f, 0.f, 0.f, 0.f};

#pragma unroll
  for (int t = 0; t < 2; ++t) {
    int n = t * 512 + tid;
    int r = n >> 3;
    int kc = ((n & 7) ^ (r + (r >> 3))) & 7;
    gld_lds16(qkv + ((size_t)b * 1024 + r) * 3072 + 1024 + h * 64 + kc * 8,
              sK[0] + n * 8);
    int d = n >> 4, s = n & 15;
    int c = s ^ (d & 7);
    gld_lds16(vbase + (size_t)d * 1024 + c * 8, sV[0] + n * 8);
  }

  for (int kt = 0; kt < 8; ++kt) {
    const int buf = kt & 1;
    __syncthreads();
    if (kt < 7) {
#pragma unroll
      for (int t = 0; t < 2; ++t) {
        int n = t * 512 + tid;
        int r = n >> 3;
        int kc = ((n & 7) ^ (r + (r >> 3))) & 7;
        gld_lds16(qkv + ((size_t)b * 1024 + (kt + 1) * 128 + r) * 3072 + 1024 +
                      h * 64 + kc * 8,
                  sK[buf ^ 1] + n * 8);
        int d = n >> 4, s = n & 15;
        int c = s ^ (d & 7);
        gld_lds16(vbase + (size_t)d * 1024 + (kt + 1) * 128 + c * 8,
                  sV[buf ^ 1] + n * 8);
      }
    }
    const bf16_t* sKb = sK[buf];
    const bf16_t* sVb = sV[buf];

#pragma unroll
    for (int ch = 0; ch < 4; ++ch) {
      bf16x8 ak[2][2];
#pragma unroll
      for (int kk = 0; kk < 2; ++kk)
#pragma unroll
        for (int ks = 0; ks < 2; ++ks)
          ak[kk][ks] = *(const bf16x8*)&sKb[sw64(ch * 32 + kk * 16 + l,
                                                 ks * 4 + quad)];
      bf16x8 va[4];
#pragma unroll
      for (int jd = 0; jd < 4; ++jd)
        va[jd] = *(const bf16x8*)&sVb[(jd * 16 + l) * 128 +
                                      (((ch * 4 + quad) ^ (l & 7)) << 3)];
#pragma unroll
      for (int i = 0; i < 2; ++i) {
        __builtin_amdgcn_s_setprio(1);
        f32x4 st0 = {0.f, 0.f, 0.f, 0.f}, st1 = {0.f, 0.f, 0.f, 0.f};
        st0 = mfma16(ak[0][0], bq[i][0], st0);
        st0 = mfma16(ak[0][1], bq[i][1], st0);
        st1 = mfma16(ak[1][0], bq[i][0], st1);
        st1 = mfma16(ak[1][1], bq[i][1], st1);
        bf16x8 pc;
#pragma unroll
        for (int t = 0; t < 4; ++t) {
          pc[t] = (bf16_t)exp2c(st0[t]);
          pc[4 + t] = (bf16_t)exp2c(st1[t]);
        }
#pragma unroll
        for (int jd = 0; jd < 4; ++jd)
          o[i][jd] = mfma16(va[jd], pc, o[i][jd]);
        __builtin_amdgcn_s_setprio(0);
      }
    }
  }
#pragma unroll
  for (int i = 0; i < 2; ++i) {
    size_t row = (size_t)b * 1024 + qt * 256 + wave * 32 + i * 16 + l;
#pragma unroll
    for (int jd = 0; jd < 4; ++jd) {
      bf16x4 pk;
#pragma unroll
      for (int t = 0; t < 4; ++t) pk[t] = (bf16_t)sanit(o[i][jd][t]);
      *(bf16x4*)&attn[row * 3072 + h * 64 + jd * 16 + quad * 4] = pk;
    }
  }
}

extern "C" void kernel_launch(void* const* d_in, const int* in_sizes, int n_in,
                              void* d_out, int out_size, void* d_ws, size_t ws_size,
                              hipStream_t stream) {
  (void)in_sizes; (void)n_in; (void)out_size; (void)ws_size;
  char* w = (char*)d_ws;
  bf16_t* qkv = (bf16_t*)w;                 // [0, 50331648)
  bf16_t* xb = (bf16_t*)(w + 50331648);     // -> Vts after K1
  bf16_t* Vts = xb;
  bf16_t* Wqkvb = (bf16_t*)(w + 67108864);
  bf16_t* Wprojb = (bf16_t*)(w + 73400320);
  int* flag = (int*)(w + 75497472);
  bf16_t* attn = qkv + 2048;                // V-columns of qkv, stride 3072

  detect_dtype<<<1, 256, 0, stream>>>((const unsigned short*)d_in[0], flag);
  convert_in<<<6144, 256, 0, stream>>>(d_in[0], d_in[1], d_in[2],
                                       xb, Wqkvb, Wprojb, flag);

  // K1: qkv = x @ Wqkv^T  (8192 x 3072, K=1024), 256^2 pipelined GEMM
  gemm256<<<dim3(12, 32), 512, 0, stream>>>(xb, Wqkvb, qkv);
  // K2: column-softmax denominators folded into Vts (permuted layout)
  attn_stats<<<dim3(128, 8), 256, 0, stream>>>(qkv, Vts);
  // K3: attention output -> qkv V-columns (512 thr, 256 q-rows/block)
  attn_out_k<<<dim3(128, 4), 512, 0, stream>>>(qkv, Vts, attn);
  // K4: out = attn @ Wproj^T  (8192 x 1024, K=1024), 128^2 dbuf GEMM
  gemm_bt<<<dim3(8, 64), 256, 0, stream>>>(attn, 3072, Wprojb, (bf16_t*)d_out,
                                           (float*)d_out, 1024, 1024, flag);
}

// Round 16
// 262.909 us; speedup vs baseline: 1.0813x; 1.0813x over previous
//
#include <hip/hip_runtime.h>

// B=8, T=1024, D=1024, H=16, DH=64.
// Column softmax (axis=-2): attn[q,k] = exp(S[q,k])/sum_q' exp(S[q',k]).
// rcpL folded into V (Vts = V * rcpL); C2 (DH^-0.5*log2e) folded into the
// Q-rows of Wqkv at convert time (R11) -> K2/K3 exp2 raw MFMA output.
// K3: S computed TRANSPOSED (A=K, B=Q) so P exits MFMA with q=lane&15,
// k=quad*4+t; Vts stored k-PERMUTED (chunk pos quad*8+j holds logical
// k = j<4 ? quad*4+j : 16+quad*4+(j-4)) == the 16x16x32 per-lane k-set,
// so PV = ONE K=32 MFMA per jd with pc = {exp(st0),exp(st1)} (R10).
// R13-R15 post-mortem: counted-vmcnt pipelining null at 128^2 (R13) and
// NEGATIVE at 256^2/1-block-per-CU (R15: 89us, MfmaUtil 22.8%, ds_read
// latency exposed after barrier with only 2 waves/SIMD of slack). The
// 2-phase 128^2 static-dbuf structure is this session's GEMM floor.
// R16: revert to R12 module (best stable, 266-272) + two zero-risk cuts:
// (a) detect_dtype launch removed -- convert_in blocks self-probe the
//     first 256 u16 of x (512B, L2-hot; bf16 exp<=134 deterministic,
//     fp32 mantissa-words ~uniform -> P(miss) ~ 0.625^128); i==0 writes
//     the flag to workspace for K4's output-dtype branch.
// (b) K2 setprio(1) around MFMA pairs (T5, isolated this time -- R11's
//     test was confounded by the register-spill of the Q-prefetch).

typedef __bf16 bf16_t;
typedef __bf16 bf16x8 __attribute__((ext_vector_type(8)));
typedef __bf16 bf16x4 __attribute__((ext_vector_type(4)));
typedef float f32x4 __attribute__((ext_vector_type(4)));
typedef unsigned short u16x8 __attribute__((ext_vector_type(8)));

#define DEV __device__ __forceinline__
#define C2 0.18033688f  // DH^-0.5 * log2(e), folded into Q-rows of Wqkv

DEV void gld_lds16(const bf16_t* g, bf16_t* l) {
  __builtin_amdgcn_global_load_lds(
      (const __attribute__((address_space(1))) unsigned int*)g,
      (__attribute__((address_space(3))) unsigned int*)l, 16, 0, 0);
}

// exp2 via v_exp_f32; upper clamp only (underflow->0 fine); finite always.
DEV float exp2c(float x) { return __builtin_amdgcn_exp2f(fminf(x, 30.f)); }
DEV float sanit(float v) { return (v == v) ? fminf(fmaxf(v, -1e4f), 1e4f) : 0.f; }

// Swizzled chunk (8 bf16 = 16B) offsets in elements. Swizzle baked into the
// staging GLOBAL address so the LDS side stays linear (global_load_lds req).
DEV int sw64(int r, int kc) { return r * 64 + (((kc ^ (r + (r >> 3))) & 7) << 3); }

DEV f32x4 mfma16(bf16x8 a, bf16x8 b, f32x4 c) {
  return __builtin_amdgcn_mfma_f32_16x16x32_bf16(a, b, c, 0, 0, 0);
}

// ---- canonicalize inputs to bf16; per-block dtype probe; Q-rows x C2 -------
// Probe: sample x[0..255] as u16. bf16 data -> all exp fields <= ~134
// (deterministic); fp32 misread -> ~128 mantissa-low words, each ~uniform,
// max exp >= 160 with probability 1 - 0.625^128. All blocks agree.
__global__ void convert_in(const void* __restrict__ x, const void* __restrict__ wq,
                           const void* __restrict__ wp, bf16_t* __restrict__ xb,
                           bf16_t* __restrict__ wqb, bf16_t* __restrict__ wpb,
                           int* __restrict__ flagp) {
  __shared__ int smax;
  if (threadIdx.x == 0) smax = 0;
  __syncthreads();
  {
    int e = (((const unsigned short*)x)[threadIdx.x] >> 7) & 0xFF;
    atomicMax(&smax, e);
  }
  __syncthreads();
  const bool isF32 = smax >= 160;

  int i = blockIdx.x * 256 + threadIdx.x;  // vec8 index, total 1572864
  if (i == 0) *flagp = isF32 ? 1 : 0;      // for K4's output-dtype branch
  const void* src;
  bf16_t* dst;
  int off;
  bool isQ = false;
  if (i < 1048576) { src = x; dst = xb; off = i; }
  else if (i < 1441792) {
    src = wq; dst = wqb; off = i - 1048576;
    isQ = off < 131072;  // rows 0..1023 of Wqkv
  } else { src = wp; dst = wpb; off = i - 1441792; }
  if (isF32) {
    const float s = isQ ? C2 : 1.0f;
    const float4* sp = (const float4*)src;
    float4 a = sp[off * 2], b = sp[off * 2 + 1];
    bf16x8 o;
    o[0] = (bf16_t)(a.x * s); o[1] = (bf16_t)(a.y * s);
    o[2] = (bf16_t)(a.z * s); o[3] = (bf16_t)(a.w * s);
    o[4] = (bf16_t)(b.x * s); o[5] = (bf16_t)(b.y * s);
    o[6] = (bf16_t)(b.z * s); o[7] = (bf16_t)(b.w * s);
    *(bf16x8*)(dst + (size_t)off * 8) = o;
  } else {
    u16x8 v = ((const u16x8*)src)[off];
    if (isQ) {
      bf16x8 bsrc = __builtin_bit_cast(bf16x8, v);
      bf16x8 o;
#pragma unroll
      for (int t = 0; t < 8; ++t) o[t] = (bf16_t)((float)bsrc[t] * C2);
      *(bf16x8*)(dst + (size_t)off * 8) = o;
    } else {
      ((u16x8*)dst)[off] = v;
    }
  }
}

// --------- C[m][n] = sum_k A[m][k]*B[n][k], 128x128 tile, BK=64x2 -----------
// Statically-unrolled LDS double-buffer (R7 body, best-measured e2e):
//   barrier; stage(buf1,k+64); compute(buf0); barrier; stage(buf0,k+128);
//   compute(buf1).  4 distinct __shared__ arrays -> alias analysis resolves
// (R4 lesson). Chunked bijective XCD swizzle (nwg % 8 == 0).
__global__ __launch_bounds__(256, 2)
void gemm_bt(const bf16_t* __restrict__ A, int lda, const bf16_t* __restrict__ B,
             bf16_t* __restrict__ Cb, float* __restrict__ Cf, int ldc,
             int K, const int* __restrict__ f32flag) {
  __shared__ bf16_t sA0[128 * 64];  // 16 KB
  __shared__ bf16_t sB0[128 * 64];
  __shared__ bf16_t sA1[128 * 64];
  __shared__ bf16_t sB1[128 * 64];
  const int tid = threadIdx.x;
  const int wave = tid >> 6, lane = tid & 63;
  const int l = lane & 15, quad = lane >> 4;
  const int nwg = gridDim.x * gridDim.y;
  const int bid = blockIdx.y * gridDim.x + blockIdx.x;
  const int sb = (bid & 7) * (nwg >> 3) + (bid >> 3);
  const int row0 = (sb / gridDim.x) * 128, col0 = (sb % gridDim.x) * 128;
  const int wm = (wave >> 1) * 64, wn = (wave & 1) * 64;
  f32x4 acc[4][4];
#pragma unroll
  for (int i = 0; i < 4; ++i)
#pragma unroll
    for (int j = 0; j < 4; ++j) acc[i][j] = f32x4{0.f, 0.f, 0.f, 0.f};

#define STAGE_G(sa, sb_, kk)                                                  \
  {                                                                           \
    _Pragma("unroll") for (int t = 0; t < 4; ++t) {                           \
      int n = t * 256 + tid;                                                  \
      int r = n >> 3;                                                         \
      int kc = ((n & 7) ^ (r + (r >> 3))) & 7;                                \
      gld_lds16(A + (size_t)(row0 + r) * lda + (kk) + kc * 8, (sa) + n * 8);  \
      gld_lds16(B + (size_t)(col0 + r) * K + (kk) + kc * 8, (sb_) + n * 8);   \
    }                                                                         \
  }

#define COMPUTE_G(sa, sb_)                                                    \
  {                                                                           \
    _Pragma("unroll") for (int ks = 0; ks < 2; ++ks) {                        \
      bf16x8 af[4], bfr[4];                                                   \
      _Pragma("unroll") for (int i = 0; i < 4; ++i) af[i] =                   \
          *(const bf16x8*)&(sa)[sw64(wm + i * 16 + l, ks * 4 + quad)];        \
      _Pragma("unroll") for (int j = 0; j < 4; ++j) bfr[j] =                  \
          *(const bf16x8*)&(sb_)[sw64(wn + j * 16 + l, ks * 4 + quad)];       \
      _Pragma("unroll") for (int i = 0; i < 4; ++i)                           \
          _Pragma("unroll") for (int j = 0; j < 4; ++j) acc[i][j] =           \
              mfma16(af[i], bfr[j], acc[i][j]);                               \
    }                                                                         \
  }

  STAGE_G(sA0, sB0, 0);
  for (int k0 = 0; k0 < K; k0 += 128) {
    __syncthreads();  // buf0 staged; also orders prev compute(buf1) vs refill
    if (k0 + 64 < K) STAGE_G(sA1, sB1, k0 + 64);
    COMPUTE_G(sA0, sB0);
    __syncthreads();  // buf1 staged; orders compute(buf0) vs buf0 refill
    if (k0 + 128 < K) STAGE_G(sA0, sB0, k0 + 128);
    COMPUTE_G(sA1, sB1);
  }
#undef STAGE_G
#undef COMPUTE_G

  const bool of32 = (f32flag != nullptr) && (*f32flag != 0);
#pragma unroll
  for (int i = 0; i < 4; ++i) {
    int rr = row0 + wm + i * 16 + quad * 4;
#pragma unroll
    for (int j = 0; j < 4; ++j) {
      int cc = col0 + wn + j * 16 + l;
#pragma unroll
      for (int t = 0; t < 4; ++t) {
        float v = sanit(acc[i][j][t]);
        size_t idx = (size_t)(rr + t) * ldc + cc;
        if (of32) Cf[idx] = v; else Cb[idx] = (bf16_t)v;
      }
    }
  }
}

// ------------- K2: column sumexp L[k]; write Vts = V * (1/L) -----------------
// R12 body + isolated T5 setprio. Q pre-scaled by C2 -> exp2 on raw MFMA
// output. Per-lane accj[] defers reduction: 8 atomics/wave. Vts write is
// k-PERMUTED within each 32-chunk (see K3 header comment).
__global__ __launch_bounds__(256, 4)
void attn_stats(const bf16_t* __restrict__ qkv, bf16_t* __restrict__ Vts) {
  __shared__ bf16_t sK[128 * 64];
  __shared__ bf16_t sV[128 * 64];
  __shared__ float sL[128];
  const int bh = blockIdx.x, kt = blockIdx.y;
  const int b = bh >> 4, h = bh & 15;
  const int tid = threadIdx.x, wave = tid >> 6, lane = tid & 63;
  const int l = lane & 15, quad = lane >> 4;
  const size_t rowK = (size_t)b * 1024 + kt * 128;

  // stage V-tile and K-tile (swizzled)
#pragma unroll
  for (int t = 0; t < 4; ++t) {
    int base = wave * 256 + t * 64;
    int n = base + lane;
    int r = n >> 3;
    int kc = ((n & 7) ^ (r + (r >> 3))) & 7;
    gld_lds16(qkv + (rowK + r) * 3072 + 2048 + h * 64 + kc * 8, sV + base * 8);
    gld_lds16(qkv + (rowK + r) * 3072 + 1024 + h * 64 + kc * 8, sK + base * 8);
  }
  if (tid < 128) sL[tid] = 0.f;
  __syncthreads();

  float accj[8];
#pragma unroll
  for (int j = 0; j < 8; ++j) accj[j] = 0.f;

  for (int qt = 0; qt < 8; ++qt) {
    bf16x8 aq[2][2];
#pragma unroll
    for (int i = 0; i < 2; ++i)
#pragma unroll
      for (int ks = 0; ks < 2; ++ks)
        aq[i][ks] = *(const bf16x8*)&qkv[((size_t)b * 1024 + qt * 128 + wave * 32 +
                                          i * 16 + l) * 3072 + h * 64 +
                                         (ks * 4 + quad) * 8];
#pragma unroll
    for (int j = 0; j < 8; ++j) {
      f32x4 s0 = {0.f, 0.f, 0.f, 0.f}, s1 = {0.f, 0.f, 0.f, 0.f};
      __builtin_amdgcn_s_setprio(1);
#pragma unroll
      for (int ks = 0; ks < 2; ++ks) {
        bf16x8 bk = *(const bf16x8*)&sK[sw64(j * 16 + l, ks * 4 + quad)];
        s0 = mfma16(aq[0][ks], bk, s0);
        s1 = mfma16(aq[1][ks], bk, s1);
      }
      __builtin_amdgcn_s_setprio(0);
#pragma unroll
      for (int t = 0; t < 4; ++t)
        accj[j] += exp2c(s0[t]) + exp2c(s1[t]);
    }
  }
#pragma unroll
  for (int j = 0; j < 8; ++j) {
    float v = accj[j];
    v += __shfl_xor(v, 16);
    v += __shfl_xor(v, 32);
    if (lane < 16) atomicAdd(&sL[j * 16 + l], v);
  }
  __syncthreads();
  if (tid < 128) sL[tid] = 1.0f / fmaxf(sL[tid], 1e-20f);
  __syncthreads();

  // write V transposed, scaled, k-permuted:
  // storage pos (chunk base | i) holds logical k = base | kk*16 | quad*4 | t
  // where kk=(i>>2), quad=(k0>>3)&3, t=i&3.
#pragma unroll
  for (int t = 0; t < 4; ++t) {
    int u = t * 256 + tid;
    int d = u >> 4, k0 = (u & 15) * 8;
    bf16x8 pk;
#pragma unroll
    for (int i = 0; i < 8; ++i) {
      int kl = (k0 & ~31) | ((i >> 2) << 4) | (((k0 >> 3) & 3) << 2) | (i & 3);
      float v = (float)sV[sw64(kl, d >> 3) + (d & 7)];
      pk[i] = (bf16_t)(v * sL[kl]);
    }
    *(bf16x8*)&Vts[((size_t)bh * 64 + d) * 1024 + kt * 128 + k0] = pk;
  }
}

// ------------- K3: O[q][d] = sum_k exp2(Ss[q,k]) * Vts[d][k] -----------------
// R12 body (frozen). PV = single K=32 MFMA per jd; P stays in registers.
// K/Vts tiles staged in LDS (global_load_lds, dbuf, prefetched 1 kt ahead);
// Vts LDS [64 d][128 k] with chunk ^= d&7 swizzle (2-way-free reads).
// 512 threads, LDS 64KB -> 2 blocks/CU -> 16 waves/CU. T5 setprio.
__global__ __launch_bounds__(512, 4)
void attn_out_k(const bf16_t* __restrict__ qkv, const bf16_t* __restrict__ Vts,
                bf16_t* __restrict__ attn) {
  __shared__ bf16_t sK[2][128 * 64];  // 16 KB x2: [k][dh], sw64-swizzled
  __shared__ bf16_t sV[2][64 * 128];  // 16 KB x2: [d][k], chunk^= d&7
  const int bh = blockIdx.x, qt = blockIdx.y;  // qt in [0,4): 256 q-rows/block
  const int b = bh >> 4, h = bh & 15;
  const int tid = threadIdx.x, wave = tid >> 6, lane = tid & 63;
  const int l = lane & 15, quad = lane >> 4;
  const bf16_t* qbase = qkv + (size_t)b * 3145728 + h * 64;  // row stride 3072
  const bf16_t* vbase = Vts + (size_t)bh * 65536;            // row stride 1024

  // Q B-fragments (loop-invariant): B[n=q][dk = ks*32 + quad*8 + j]
  bf16x8 bq[2][2];
#pragma unroll
  for (int i = 0; i < 2; ++i)
#pragma unroll
    for (int ks = 0; ks < 2; ++ks)
      bq[i][ks] = *(const bf16x8*)&qbase[(size_t)(qt * 256 + wave * 32 + i * 16 + l) *
                                             3072 + ks * 32 + quad * 8];
  f32x4 o[2][4];  // o[i=qtile][jd=dtile] : D[m=d][n=q]
#pragma unroll
  for (int i = 0; i < 2; ++i)
#pragma unroll
    for (int jd = 0; jd < 4; ++jd) o[i][jd] = f32x4{0.f, 0.f, 0.f, 0.f};

  // stage kt=0 -> buf 0 (K: 1024 chunks; V: 1024 chunks; 2 each per thread)
#pragma unroll
  for (int t = 0; t < 2; ++t) {
    int n = t * 512 + tid;
    int r = n >> 3;
    int kc = ((n & 7) ^ (r + (r >> 3))) & 7;
    gld_lds16(qkv + ((size_t)b * 1024 + r) * 3072 + 1024 + h * 64 + kc * 8,
              sK[0] + n * 8);
    int d = n >> 4, s = n & 15;
    int c = s ^ (d & 7);
    gld_lds16(vbase + (size_t)d * 1024 + c * 8, sV[0] + n * 8);
  }

  for (int kt = 0; kt < 8; ++kt) {
    const int buf = kt & 1;
    __syncthreads();  // drains stage(kt); orders buf^1 refill vs prev reads
    if (kt < 7) {
#pragma unroll
      for (int t = 0; t < 2; ++t) {
        int n = t * 512 + tid;
        int r = n >> 3;
        int kc = ((n & 7) ^ (r + (r >> 3))) & 7;
        gld_lds16(qkv + ((size_t)b * 1024 + (kt + 1) * 128 + r) * 3072 + 1024 +
                      h * 64 + kc * 8,
                  sK[buf ^ 1] + n * 8);
        int d = n >> 4, s = n & 15;
        int c = s ^ (d & 7);
        gld_lds16(vbase + (size_t)d * 1024 + (kt + 1) * 128 + c * 8,
                  sV[buf ^ 1] + n * 8);
      }
    }
    const bf16_t* sKb = sK[buf];
    const bf16_t* sVb = sV[buf];

#pragma unroll
    for (int ch = 0; ch < 4; ++ch) {  // 32-k chunks
      // K A-frags: A[m=k=ch*32+kk*16+l][dk] -- i-invariant, hoisted
      bf16x8 ak[2][2];
#pragma unroll
      for (int kk = 0; kk < 2; ++kk)
#pragma unroll
        for (int ks = 0; ks < 2; ++ks)
          ak[kk][ks] = *(const bf16x8*)&sKb[sw64(ch * 32 + kk * 16 + l,
                                                 ks * 4 + quad)];
      // Vts A-frags from LDS: row d=jd*16+l, logical chunk ch*4+quad,
      // storage chunk = logical ^ (l&7)  (d&7 == l&7 since jd*16%8==0)
      bf16x8 va[4];
#pragma unroll
      for (int jd = 0; jd < 4; ++jd)
        va[jd] = *(const bf16x8*)&sVb[(jd * 16 + l) * 128 +
                                      (((ch * 4 + quad) ^ (l & 7)) << 3)];
#pragma unroll
      for (int i = 0; i < 2; ++i) {  // q-tiles
        __builtin_amdgcn_s_setprio(1);
        // Ss^T tiles (kk=0,1); Q pre-scaled by C2
        f32x4 st0 = {0.f, 0.f, 0.f, 0.f}, st1 = {0.f, 0.f, 0.f, 0.f};
        st0 = mfma16(ak[0][0], bq[i][0], st0);
        st0 = mfma16(ak[0][1], bq[i][1], st0);
        st1 = mfma16(ak[1][0], bq[i][0], st1);
        st1 = mfma16(ak[1][1], bq[i][1], st1);
        // pc = exp2(Ss^T) concatenated: slot quad*8+j <-> Vts storage slot
        bf16x8 pc;
#pragma unroll
        for (int t = 0; t < 4; ++t) {
          pc[t] = (bf16_t)exp2c(st0[t]);
          pc[4 + t] = (bf16_t)exp2c(st1[t]);
        }
#pragma unroll
        for (int jd = 0; jd < 4; ++jd)
          o[i][jd] = mfma16(va[jd], pc, o[i][jd]);
        __builtin_amdgcn_s_setprio(0);
      }
    }
  }
  // epilogue: q = qt*256+wave*32+i*16+l, d = jd*16+quad*4+{0..3} -> 8B stores
#pragma unroll
  for (int i = 0; i < 2; ++i) {
    size_t row = (size_t)b * 1024 + qt * 256 + wave * 32 + i * 16 + l;
#pragma unroll
    for (int jd = 0; jd < 4; ++jd) {
      bf16x4 pk;
#pragma unroll
      for (int t = 0; t < 4; ++t) pk[t] = (bf16_t)sanit(o[i][jd][t]);
      *(bf16x4*)&attn[row * 3072 + h * 64 + jd * 16 + quad * 4] = pk;
    }
  }
}

extern "C" void kernel_launch(void* const* d_in, const int* in_sizes, int n_in,
                              void* d_out, int out_size, void* d_ws, size_t ws_size,
                              hipStream_t stream) {
  (void)in_sizes; (void)n_in; (void)out_size; (void)ws_size;
  char* w = (char*)d_ws;
  bf16_t* qkv = (bf16_t*)w;                 // [0, 50331648)
  bf16_t* xb = (bf16_t*)(w + 50331648);     // [50331648, 67108864) -> Vts after K1
  bf16_t* Vts = xb;
  bf16_t* Wqkvb = (bf16_t*)(w + 67108864);  // [67108864, 73400320)
  bf16_t* Wprojb = (bf16_t*)(w + 73400320); // [73400320, 75497472)
  int* flag = (int*)(w + 75497472);
  bf16_t* attn = qkv + 2048;                // V-columns of qkv, stride 3072

  // convert: self-probing dtype (writes flag for K4); Q-rows scaled by C2
  convert_in<<<6144, 256, 0, stream>>>(d_in[0], d_in[1], d_in[2],
                                       xb, Wqkvb, Wprojb, flag);

  // K1: qkv = x @ Wqkv^T  (8192 x 3072, K=1024), grid 24*64=1536 (%8==0)
  gemm_bt<<<dim3(24, 64), 256, 0, stream>>>(xb, 1024, Wqkvb, qkv, nullptr, 3072,
                                            1024, nullptr);
  // K2: column-softmax denominators folded into Vts (permuted layout)
  attn_stats<<<dim3(128, 8), 256, 0, stream>>>(qkv, Vts);
  // K3: attention output -> qkv V-columns (512 thr, 256 q-rows/block)
  attn_out_k<<<dim3(128, 4), 512, 0, stream>>>(qkv, Vts, attn);
  // K4: out = attn @ Wproj^T  (8192 x 1024, K=1024), grid 8*64=512 (%8==0)
  gemm_bt<<<dim3(8, 64), 256, 0, stream>>>(attn, 3072, Wprojb, (bf16_t*)d_out,
                                           (float*)d_out, 1024, 1024, flag);
}